// Round 1
// baseline (908.264 us; speedup 1.0000x reference)
//
#include <hip/hip_runtime.h>
#include <hip/hip_bf16.h>
#include <stdint.h>

#define TOKENS 4096
#define IN_F   4096
#define OUT_F  11008
#define NGROUPS 32

typedef __bf16 bf16_t;
typedef __bf16 bf16x8 __attribute__((ext_vector_type(8)));
typedef float  f32x4  __attribute__((ext_vector_type(4)));

// ---------------- pre-pass: x fp32 -> bf16 ----------------
__global__ __launch_bounds__(256)
void cvt_x_kernel(const float* __restrict__ x, bf16_t* __restrict__ xb) {
    int v = blockIdx.x * 256 + threadIdx.x;           // one vec8 per thread
    const float4* x4 = (const float4*)x;
    float4 a = x4[2 * v], b = x4[2 * v + 1];
    bf16x8 o;
    o[0] = (bf16_t)a.x; o[1] = (bf16_t)a.y; o[2] = (bf16_t)a.z; o[3] = (bf16_t)a.w;
    o[4] = (bf16_t)b.x; o[5] = (bf16_t)b.y; o[6] = (bf16_t)b.z; o[7] = (bf16_t)b.w;
    *(bf16x8*)(xb + 8 * v) = o;
}

// ---------------- pre-pass: W int32 -> bf16 * group-scale ----------------
__global__ __launch_bounds__(256)
void dequant_w_kernel(const int* __restrict__ w, const float* __restrict__ scale,
                      bf16_t* __restrict__ wb) {
    int v = blockIdx.x * 256 + threadIdx.x;           // one vec8 per thread
    int o = v >> 9;                                   // 512 vec8 per row (4096/8)
    int g = (v & 511) >> 4;                           // k/128 group
    float s = scale[o * NGROUPS + g];
    const int4* w4 = (const int4*)w;
    int4 a = w4[2 * v], b = w4[2 * v + 1];
    bf16x8 ob;
    ob[0] = (bf16_t)((float)a.x * s); ob[1] = (bf16_t)((float)a.y * s);
    ob[2] = (bf16_t)((float)a.z * s); ob[3] = (bf16_t)((float)a.w * s);
    ob[4] = (bf16_t)((float)b.x * s); ob[5] = (bf16_t)((float)b.y * s);
    ob[6] = (bf16_t)((float)b.z * s); ob[7] = (bf16_t)((float)b.w * s);
    *(bf16x8*)(wb + 8 * v) = ob;
}

// ---------------- GEMM: C = A[M,K] * B[N,K]^T + bias ----------------
#define BM 128
#define BN 128
#define BK 64

__device__ __forceinline__ void async16(const void* g, void* l) {
    __builtin_amdgcn_global_load_lds(
        (const __attribute__((address_space(1))) uint32_t*)g,
        (__attribute__((address_space(3))) uint32_t*)l, 16, 0, 0);
}

__global__ __launch_bounds__(256)
void gemm_bt_kernel(const bf16_t* __restrict__ A,
                    const bf16_t* __restrict__ B,
                    const float* __restrict__ bias,
                    float* __restrict__ C) {
    // LDS tiles: row-major [128][64] bf16, 16B column-blocks XOR-swizzled by (row&7).
    // No padding: global_load_lds writes wave-base + lane*16, so layout is fixed by
    // lane order; the swizzle is applied by permuting the *global source* per lane.
    __shared__ bf16_t sA[BM * BK];
    __shared__ bf16_t sB[BN * BK];

    const int tid    = threadIdx.x;
    const int lane   = tid & 63;
    const int wave   = tid >> 6;
    const int wm     = wave >> 1;      // wave tile row (0..1)
    const int wn     = wave & 1;       // wave tile col (0..1)
    const int lane15 = lane & 15;
    const int quad   = lane >> 4;
    const int bm     = blockIdx.y * BM;
    const int bn     = blockIdx.x * BN;

    f32x4 acc[4][4] = {};

    // staging source geometry (fixed over K-iters): slot s = r*256+tid covers
    // row m = s>>3, column-block c = s&7; source k-block is c ^ (m&7)
    int sm[4], sc[4];
    #pragma unroll
    for (int r = 0; r < 4; ++r) {
        int s = r * 256 + tid;
        sm[r] = s >> 3;
        sc[r] = (s & 7) ^ (sm[r] & 7);
    }
    bf16_t* lA = sA + wave * 64 * 8;   // wave-uniform LDS base (+ r*2048 per round)
    bf16_t* lB = sB + wave * 64 * 8;

    for (int k0 = 0; k0 < IN_F; k0 += BK) {
        #pragma unroll
        for (int r = 0; r < 4; ++r) {
            const bf16_t* gA = A + (bm + sm[r]) * IN_F + k0 + sc[r] * 8;
            const bf16_t* gB = B + (bn + sm[r]) * IN_F + k0 + sc[r] * 8;
            async16(gA, lA + r * 2048);
            async16(gB, lB + r * 2048);
        }
        __syncthreads();

        #pragma unroll
        for (int kk = 0; kk < 2; ++kk) {
            const int bblk = kk * 4 + quad;            // global k-block (0..7)
            bf16x8 aF[4], bF[4];
            #pragma unroll
            for (int i = 0; i < 4; ++i) {
                int mr = wm * 64 + i * 16 + lane15;
                aF[i] = *(const bf16x8*)(sA + mr * BK + ((bblk ^ (mr & 7)) * 8));
                int nr = wn * 64 + i * 16 + lane15;
                bF[i] = *(const bf16x8*)(sB + nr * BK + ((bblk ^ (nr & 7)) * 8));
            }
            #pragma unroll
            for (int i = 0; i < 4; ++i)
                #pragma unroll
                for (int j = 0; j < 4; ++j)
                    acc[i][j] = __builtin_amdgcn_mfma_f32_16x16x32_bf16(
                        aF[i], bF[j], acc[i][j], 0, 0, 0);
        }
        __syncthreads();
    }

    // epilogue: C/D layout col=lane&15, row=quad*4+reg (m89/m91-verified)
    #pragma unroll
    for (int j = 0; j < 4; ++j) {
        int n = bn + wn * 64 + j * 16 + lane15;
        float bj = bias[n];
        #pragma unroll
        for (int i = 0; i < 4; ++i) {
            int m0 = bm + wm * 64 + i * 16 + quad * 4;
            #pragma unroll
            for (int r = 0; r < 4; ++r)
                C[(m0 + r) * OUT_F + n] = acc[i][j][r] + bj;
        }
    }
}

extern "C" void kernel_launch(void* const* d_in, const int* in_sizes, int n_in,
                              void* d_out, int out_size, void* d_ws, size_t ws_size,
                              hipStream_t stream) {
    const float* x     = (const float*)d_in[0];
    const int*   w     = (const int*)d_in[1];
    const float* scale = (const float*)d_in[2];
    const float* bias  = (const float*)d_in[3];
    float* out = (float*)d_out;

    // workspace: [x_bf16 : 33,554,432 B][w_bf16 : 90,177,536 B] = 123,731,968 B
    bf16_t* xb = (bf16_t*)d_ws;
    bf16_t* wb = (bf16_t*)((char*)d_ws + (size_t)TOKENS * IN_F * 2);

    cvt_x_kernel<<<TOKENS * IN_F / (8 * 256), 256, 0, stream>>>(x, xb);
    dequant_w_kernel<<<OUT_F * IN_F / (8 * 256), 256, 0, stream>>>(w, scale, wb);

    dim3 grid(OUT_F / BN, TOKENS / BM);
    gemm_bt_kernel<<<grid, 256, 0, stream>>>(xb, wb, bias, out);
}

// Round 2
// 866.423 us; speedup vs baseline: 1.0483x; 1.0483x over previous
//
#include <hip/hip_runtime.h>
#include <hip/hip_bf16.h>
#include <stdint.h>

#define TOKENS 4096
#define IN_F   4096
#define OUT_F  11008
#define NGROUPS 32

typedef __bf16 bf16_t;
typedef __bf16 bf16x8 __attribute__((ext_vector_type(8)));
typedef float  f32x4  __attribute__((ext_vector_type(4)));

// ---------------- pre-pass: x fp32 -> bf16 ----------------
__global__ __launch_bounds__(256)
void cvt_x_kernel(const float* __restrict__ x, bf16_t* __restrict__ xb) {
    int v = blockIdx.x * 256 + threadIdx.x;           // one vec8 per thread
    const float4* x4 = (const float4*)x;
    float4 a = x4[2 * v], b = x4[2 * v + 1];
    bf16x8 o;
    o[0] = (bf16_t)a.x; o[1] = (bf16_t)a.y; o[2] = (bf16_t)a.z; o[3] = (bf16_t)a.w;
    o[4] = (bf16_t)b.x; o[5] = (bf16_t)b.y; o[6] = (bf16_t)b.z; o[7] = (bf16_t)b.w;
    *(bf16x8*)(xb + 8 * v) = o;
}

// ---------------- pre-pass: W int32 -> bf16 * group-scale ----------------
__global__ __launch_bounds__(256)
void dequant_w_kernel(const int* __restrict__ w, const float* __restrict__ scale,
                      bf16_t* __restrict__ wb) {
    int v = blockIdx.x * 256 + threadIdx.x;           // one vec8 per thread
    int o = v >> 9;                                   // 512 vec8 per row (4096/8)
    int g = (v & 511) >> 4;                           // k/128 group
    float s = scale[o * NGROUPS + g];
    const int4* w4 = (const int4*)w;
    int4 a = w4[2 * v], b = w4[2 * v + 1];
    bf16x8 ob;
    ob[0] = (bf16_t)((float)a.x * s); ob[1] = (bf16_t)((float)a.y * s);
    ob[2] = (bf16_t)((float)a.z * s); ob[3] = (bf16_t)((float)a.w * s);
    ob[4] = (bf16_t)((float)b.x * s); ob[5] = (bf16_t)((float)b.y * s);
    ob[6] = (bf16_t)((float)b.z * s); ob[7] = (bf16_t)((float)b.w * s);
    *(bf16x8*)(wb + 8 * v) = ob;
}

// ---------------- GEMM: C = A[M,K] * B[N,K]^T + bias ----------------
#define BM 128
#define BN 128
#define BK 64
#define MTILES (TOKENS / BM)   // 32
#define NTILES (OUT_F / BN)    // 86

__device__ __forceinline__ void async16(const void* g, void* l) {
    __builtin_amdgcn_global_load_lds(
        (const __attribute__((address_space(1))) uint32_t*)g,
        (__attribute__((address_space(3))) uint32_t*)l, 16, 0, 0);
}

__global__ __launch_bounds__(256)
void gemm_bt_kernel(const bf16_t* __restrict__ A,
                    const bf16_t* __restrict__ B,
                    const float* __restrict__ bias,
                    float* __restrict__ C) {
    __shared__ bf16_t sA[BM * BK];
    __shared__ bf16_t sB[BN * BK];

    // ---- XCD-aware swizzle: block lin -> XCD lin&7 (HW round-robin).
    // Each XCD owns a 4-Mrow x 86-Ncol strip of C; order n-major, m inner.
    // Per-XCD L2 working set: A-strip 4 MB (resident) + current B-tile 1 MB;
    // B streams ONCE per XCD instead of ~16 refills.
    const int lin    = blockIdx.x;
    const int xcd    = lin & 7;
    const int idx    = lin >> 3;          // 0..343
    const int mlocal = idx & 3;           // 4 m-tiles per XCD strip
    const int ncol   = idx >> 2;          // 0..85
    const int bm     = (xcd * 4 + mlocal) * BM;
    const int bn     = ncol * BN;

    const int tid    = threadIdx.x;
    const int lane   = tid & 63;
    const int wave   = tid >> 6;
    const int wm     = wave >> 1;
    const int wn     = wave & 1;
    const int lane15 = lane & 15;
    const int quad   = lane >> 4;

    f32x4 acc[4][4] = {};

    // staging source geometry: slot s = r*256+tid covers row m = s>>3,
    // column-block c = s&7; source k-block is c ^ (m&7)  (bank swizzle)
    int sm[4], sc[4];
    #pragma unroll
    for (int r = 0; r < 4; ++r) {
        int s = r * 256 + tid;
        sm[r] = s >> 3;
        sc[r] = (s & 7) ^ (sm[r] & 7);
    }
    bf16_t* lA = sA + wave * 64 * 8;
    bf16_t* lB = sB + wave * 64 * 8;

    for (int k0 = 0; k0 < IN_F; k0 += BK) {
        #pragma unroll
        for (int r = 0; r < 4; ++r) {
            const bf16_t* gA = A + (bm + sm[r]) * IN_F + k0 + sc[r] * 8;
            const bf16_t* gB = B + (bn + sm[r]) * IN_F + k0 + sc[r] * 8;
            async16(gA, lA + r * 2048);
            async16(gB, lB + r * 2048);
        }
        __syncthreads();

        #pragma unroll
        for (int kk = 0; kk < 2; ++kk) {
            const int bblk = kk * 4 + quad;            // global k-block (0..7)
            bf16x8 aF[4], bF[4];
            #pragma unroll
            for (int i = 0; i < 4; ++i) {
                int mr = wm * 64 + i * 16 + lane15;
                aF[i] = *(const bf16x8*)(sA + mr * BK + ((bblk ^ (mr & 7)) * 8));
                int nr = wn * 64 + i * 16 + lane15;
                bF[i] = *(const bf16x8*)(sB + nr * BK + ((bblk ^ (nr & 7)) * 8));
            }
            #pragma unroll
            for (int i = 0; i < 4; ++i)
                #pragma unroll
                for (int j = 0; j < 4; ++j)
                    acc[i][j] = __builtin_amdgcn_mfma_f32_16x16x32_bf16(
                        aF[i], bF[j], acc[i][j], 0, 0, 0);
        }
        __syncthreads();
    }

    // epilogue: C/D layout col=lane&15, row=quad*4+reg (m89/m91-verified)
    #pragma unroll
    for (int j = 0; j < 4; ++j) {
        int n = bn + wn * 64 + j * 16 + lane15;
        float bj = bias[n];
        #pragma unroll
        for (int i = 0; i < 4; ++i) {
            int m0 = bm + wm * 64 + i * 16 + quad * 4;
            #pragma unroll
            for (int r = 0; r < 4; ++r)
                C[(m0 + r) * OUT_F + n] = acc[i][j][r] + bj;
        }
    }
}

extern "C" void kernel_launch(void* const* d_in, const int* in_sizes, int n_in,
                              void* d_out, int out_size, void* d_ws, size_t ws_size,
                              hipStream_t stream) {
    const float* x     = (const float*)d_in[0];
    const int*   w     = (const int*)d_in[1];
    const float* scale = (const float*)d_in[2];
    const float* bias  = (const float*)d_in[3];
    float* out = (float*)d_out;

    // workspace: [x_bf16 : 33,554,432 B][w_bf16 : 90,177,536 B]
    bf16_t* xb = (bf16_t*)d_ws;
    bf16_t* wb = (bf16_t*)((char*)d_ws + (size_t)TOKENS * IN_F * 2);

    cvt_x_kernel<<<TOKENS * IN_F / (8 * 256), 256, 0, stream>>>(x, xb);
    dequant_w_kernel<<<OUT_F * IN_F / (8 * 256), 256, 0, stream>>>(w, scale, wb);

    gemm_bt_kernel<<<MTILES * NTILES, 256, 0, stream>>>(xb, wb, bias, out);
}